// Round 7
// baseline (170.595 us; speedup 1.0000x reference)
//
#include <hip/hip_runtime.h>
#include <hip/hip_bf16.h>

#define NPOS   100
#define BATCH  1024
#define DIN    384
#define DOUT   384
#define XROW   (NPOS * DIN)      // 38400 floats, batch-dim stride of x and out
#define WSLICE (DIN * DOUT)

#define BM 64                    // batch rows per block
#define BN 384                   // FULL d_out: one block owns entire output rows
#define BK 32
#define NK (DIN / BK)            // 12 K-steps
#define PA2 392                  // A pitch (shorts): full-K rows, 784B, 16B-aligned
#define PB 40                    // B^T pitch (shorts): 80B rows (R6 layout)
#define LDS_SHORTS (BM * PA2 + BN * PB)
#define LDS_BYTES  (LDS_SHORTS * 2)   // 80,896 B -> 2 blocks/CU

typedef __attribute__((ext_vector_type(8))) short bf16x8;
typedef __attribute__((ext_vector_type(16))) float f32x16;

__device__ __forceinline__ unsigned f2bfu(float f) {
  return (unsigned)__builtin_bit_cast(unsigned short, __float2bfloat16(f));
}
__device__ __forceinline__ unsigned pack2(float a, float b) {
  return f2bfu(a) | (f2bfu(b) << 16);
}
__device__ __forceinline__ unsigned ext16(unsigned u, int h) {
  return h ? (u >> 16) : (u & 0xffffu);
}

// ds ops visible, vmcnt NOT drained (global prefetch survives the barrier)
__device__ __forceinline__ void barrier_nodrain() {
  asm volatile("s_waitcnt lgkmcnt(0)" ::: "memory");
  __builtin_amdgcn_s_barrier();
}

__global__ __launch_bounds__(512, 4) void nlinear_kernel(
    const float* __restrict__ x, const float* __restrict__ w,
    const float* __restrict__ bias, float* __restrict__ out)
{
  extern __shared__ short smem[];
  short* lA = smem;                 // [64][PA2]  full-K x tile (bf16)
  short* lB = smem + BM * PA2;      // [384][PB]  B^T, one BK chunk (R6 layout)

  const int tid  = threadIdx.x;
  const int lane = tid & 63;
  const int wave = tid >> 6;            // 8 waves: 2m x 4n
  const int wm   = wave >> 2;           // 0..1 (32 rows)
  const int wn   = wave & 3;            // 0..3 (96 cols)
  const int l31  = lane & 31;
  const int kHi  = (lane >> 5) * 8;
  const int gHalf = lane >> 5;
  const int xr   = (l31 >> 3) & 3;      // granule XOR key (R6)

  // XCD-aware bijective swizzle: 1600 = 8*200; same-slice blocks on one XCD
  const int bid   = blockIdx.x;
  const int swz   = (bid & 7) * 200 + (bid >> 3);
  const int slice = swz >> 4;           // 0..99
  const int mt    = swz & 15;           // 0..15

  const float* xbase = x    + (size_t)mt * BM * XROW + (size_t)slice * DIN;
  const float* wbase = w    + (size_t)slice * WSLICE;
  const float* bbase = bias + (size_t)slice * DOUT;
  float*       obase = out  + (size_t)mt * BM * XROW + (size_t)slice * DOUT;

  // ---- B staging map (R6 scheme, two o-regions for 384 cols) ----
  const int b_kb   = tid & 7;                 // k-block: k = kb*4+dk
  const int b_oq   = tid >> 3;                // 0..63 -> o cols 0..255
  const int b_oq2  = 64 + (tid >> 3);         // tid<256 -> o cols 256..383
  const bool p2    = (tid < 256);             // waves 0-3 (wave-uniform)
  const int b_gw   = (b_kb >> 1) ^ ((b_oq >> 1) & 3);
  const int b_gw2  = (b_kb >> 1) ^ ((b_oq2 >> 1) & 3);
  const int b_h    = b_kb & 1;

  unsigned bu1[4][2];
  unsigned bu2[4][2];

  auto G2RB = [&](int k0) {
#pragma unroll
    for (int dk = 0; dk < 4; ++dk) {
      const float4 v = *reinterpret_cast<const float4*>(
          wbase + (size_t)(k0 + b_kb * 4 + dk) * DOUT + b_oq * 4);
      bu1[dk][0] = pack2(v.x, v.y);
      bu1[dk][1] = pack2(v.z, v.w);
    }
    if (p2) {
#pragma unroll
      for (int dk = 0; dk < 4; ++dk) {
        const float4 v = *reinterpret_cast<const float4*>(
            wbase + (size_t)(k0 + b_kb * 4 + dk) * DOUT + b_oq2 * 4);
        bu2[dk][0] = pack2(v.x, v.y);
        bu2[dk][1] = pack2(v.z, v.w);
      }
    }
  };

  auto R2LB = [&]() {
#pragma unroll
    for (int c = 0; c < 4; ++c) {
      uint2 t;
      t.x = ext16(bu1[0][c >> 1], c & 1) | (ext16(bu1[1][c >> 1], c & 1) << 16);
      t.y = ext16(bu1[2][c >> 1], c & 1) | (ext16(bu1[3][c >> 1], c & 1) << 16);
      *reinterpret_cast<uint2*>(&lB[(b_oq * 4 + c) * PB + b_gw * 8 + b_h * 4]) = t;
    }
    if (p2) {
#pragma unroll
      for (int c = 0; c < 4; ++c) {
        uint2 t;
        t.x = ext16(bu2[0][c >> 1], c & 1) | (ext16(bu2[1][c >> 1], c & 1) << 16);
        t.y = ext16(bu2[2][c >> 1], c & 1) | (ext16(bu2[3][c >> 1], c & 1) << 16);
        *reinterpret_cast<uint2*>(&lB[(b_oq2 * 4 + c) * PB + b_gw2 * 8 + b_h * 4]) = t;
      }
    }
  };

  // ---- issue first B chunk, then stage the FULL x tile (coarse rows) ----
  G2RB(0);

  {
    // each row read as 3 x 512B contiguous chunks (32 lanes x float4)
    const int a_ck = tid & 31;
    const int a_r0 = tid >> 5;          // 0..15
#pragma unroll
    for (int rg = 0; rg < 4; ++rg) {
      const int row = a_r0 + 16 * rg;
      const float* rp = xbase + (size_t)row * XROW;
#pragma unroll
      for (int cc = 0; cc < 3; ++cc) {
        const float4 v = *reinterpret_cast<const float4*>(rp + cc * 128 + a_ck * 4);
        *reinterpret_cast<uint2*>(&lA[row * PA2 + cc * 128 + a_ck * 4]) =
            uint2{pack2(v.x, v.y), pack2(v.z, v.w)};
      }
    }
  }

  f32x16 acc[3];
#pragma unroll
  for (int n = 0; n < 3; ++n)
#pragma unroll
    for (int r = 0; r < 16; ++r)
      acc[n][r] = 0.f;

  R2LB();                 // write B chunk 0 (waits its vmcnt)
  barrier_nodrain();
  G2RB(BK);               // prefetch chunk 1 into regs

#pragma unroll
  for (int ks = 0; ks < NK; ++ks) {
    bf16x8 af[2];
    bf16x8 bf[2][3];
#pragma unroll
    for (int kk = 0; kk < 2; ++kk)
      af[kk] = *reinterpret_cast<const bf16x8*>(
          &lA[(wm * 32 + l31) * PA2 + ks * BK + kk * 16 + kHi]);
#pragma unroll
    for (int kk = 0; kk < 2; ++kk)
#pragma unroll
      for (int n = 0; n < 3; ++n) {
        const int g = (kk * 2 + gHalf) ^ xr;
        bf[kk][n] = *reinterpret_cast<const bf16x8*>(
            &lB[(wn * 96 + n * 32 + l31) * PB + g * 8]);
      }
#pragma unroll
    for (int kk = 0; kk < 2; ++kk)
#pragma unroll
      for (int n = 0; n < 3; ++n)
        acc[n] = __builtin_amdgcn_mfma_f32_32x32x16_bf16(
            af[kk], bf[kk][n], acc[n], 0, 0, 0);
    if (ks + 1 < NK) {
      barrier_nodrain();               // all waves done reading lB(ks)
      R2LB();                          // write chunk ks+1 (vmcnt-gated)
      if (ks + 2 < NK) G2RB((ks + 2) * BK);
      barrier_nodrain();               // chunk ks+1 visible
    }
  }

  // ---- epilogue: bias + full-row fp32 stores (block owns all 384 cols) ----
  float bv[3];
#pragma unroll
  for (int n = 0; n < 3; ++n) bv[n] = bbase[wn * 96 + n * 32 + l31];

  const int rbase = wm * 32 + ((lane >> 5) << 2);
#pragma unroll
  for (int n = 0; n < 3; ++n) {
    const int c = wn * 96 + n * 32 + l31;
#pragma unroll
    for (int r = 0; r < 16; ++r) {
      const int row = rbase + (r & 3) + 8 * (r >> 2);
      obase[(size_t)row * XROW + c] = acc[n][r] + bv[n];
    }
  }
}

extern "C" void kernel_launch(void* const* d_in, const int* in_sizes, int n_in,
                              void* d_out, int out_size, void* d_ws, size_t ws_size,
                              hipStream_t stream) {
  const float* x  = (const float*)d_in[0];
  const float* w  = (const float*)d_in[1];
  const float* b  = (const float*)d_in[2];
  float* out      = (float*)d_out;
  hipFuncSetAttribute((const void*)nlinear_kernel,
                      hipFuncAttributeMaxDynamicSharedMemorySize, LDS_BYTES);
  const int grid = NPOS * (BATCH / BM);  // 1600
  nlinear_kernel<<<grid, 512, LDS_BYTES, stream>>>(x, w, b, out);
}